// Round 18
// baseline (5552.832 us; speedup 1.0000x reference)
//
#include <hip/hip_runtime.h>
#include <hip/hip_fp16.h>

#define F_DIM 510
#define KP    512      // padded K
#define B_SZ  256
#define T_ST  512
#define MB    32       // batch rows per chunk (8 chunks)
#define NCH   8
#define NWG   512      // 2 WGs per CU
#define R1    8        // h1 ring depth
#define R2    4        // h2 ring depth
#define FSTRIDE 32     // ints per flag slot (128B; de-hotspot slices)

#define WS_FLAGS_BYTES ((size_t)NCH * 64 * FSTRIDE * 4)   // 64 KiB
#define WS_H1_OFF  WS_FLAGS_BYTES
#define WS_H2_OFF  (WS_H1_OFF + (size_t)R1 * B_SZ * KP * 2)
#define WS_X16_OFF (WS_H2_OFF + (size_t)R2 * B_SZ * KP * 2)
#define X16_BYTES  ((size_t)T_ST * B_SZ * KP * 2)

typedef _Float16 h8 __attribute__((ext_vector_type(8)));
typedef float    f4 __attribute__((ext_vector_type(4)));
typedef unsigned int u32x4 __attribute__((ext_vector_type(4)));
typedef unsigned long long u64;

__device__ __forceinline__ float sigm(float v)   { return 1.0f / (1.0f + __expf(-v)); }
__device__ __forceinline__ float tanh_f(float v) { return 1.0f - 2.0f / (__expf(2.0f * v) + 1.0f); }

__global__ void init_kernel(float* __restrict__ out, const float* __restrict__ b_lin,
                            int* __restrict__ flags) {
  int i = blockIdx.x * blockDim.x + threadIdx.x;
  if (i < NCH * 64 * FSTRIDE) flags[i] = 0;
  if (i < B_SZ * T_ST) out[i] = b_lin[0];
}

// pre-pass: x fp32 [T*B][F_DIM] -> fp16 [T*B][KP] (zero-padded)
__global__ void cvt_x_kernel(const float* __restrict__ x, _Float16* __restrict__ x16) {
  size_t i = (size_t)blockIdx.x * blockDim.x + threadIdx.x;   // 0 .. T*B*64-1
  int g = (int)(i & 63);
  size_t s = i >> 6;
  int k0 = g << 3;
  const float* src = x + s * F_DIM + k0;
  h8 v;
  if (k0 + 8 <= F_DIM) {
    #pragma unroll
    for (int e = 0; e < 4; ++e) {
      float2 p = *(const float2*)(src + 2 * e);
      v[2 * e]     = (_Float16)p.x;
      v[2 * e + 1] = (_Float16)p.y;
    }
  } else {
    #pragma unroll
    for (int e = 0; e < 8; ++e) v[e] = (_Float16)((k0 + e < F_DIM) ? src[e] : 0.0f);
  }
  *(h8*)(x16 + s * KP + k0) = v;
}

// stage fp32 x [MB][F_DIM] -> LDS fp16 [MB][KP], XOR-swizzled (fallback path)
__device__ __forceinline__ void stage_x(char* st, const float* __restrict__ src, int tid) {
  #pragma unroll
  for (int i = 0; i < 8; ++i) {
    int c  = tid + (i << 8);
    int m  = c >> 6;
    int kb = (c & 63) << 3;
    h8 v;
    const float* s = src + m * F_DIM + kb;
    if (kb + 8 <= F_DIM) {
      #pragma unroll
      for (int e = 0; e < 4; ++e) {
        float2 p = *(const float2*)(s + 2 * e);
        v[2 * e]     = (_Float16)p.x;
        v[2 * e + 1] = (_Float16)p.y;
      }
    } else {
      #pragma unroll
      for (int e = 0; e < 8; ++e) v[e] = (_Float16)((kb + e < F_DIM) ? s[e] : 0.0f);
    }
    int byte = ((m * KP + kb) << 1) ^ ((m & 7) << 4);
    *(h8*)(st + byte) = v;
  }
}

// stage fp16 x16 [MB][KP] -> LDS, XOR-swizzled (plain cached loads; split issue/use)
__device__ __forceinline__ void stage_x16(char* st, const _Float16* __restrict__ src, int tid) {
  u32x4 v[8];
  const u32x4* s = (const u32x4*)src;
  #pragma unroll
  for (int i = 0; i < 8; ++i) v[i] = s[tid + (i << 8)];
  #pragma unroll
  for (int i = 0; i < 8; ++i) {
    int c  = tid + (i << 8);
    int m  = c >> 6;
    int kc = c & 63;
    int byte = (m * 1024 + (kc << 4)) ^ ((m & 7) << 4);
    *(u32x4*)(st + byte) = v[i];
  }
}

// issue 8 PIPELINED coherent 16B loads (32 KiB tile / 256 threads)
__device__ __forceinline__ void issue_h8(u32x4* v, const _Float16* __restrict__ src, int tid) {
  const u32x4* s = (const u32x4*)src;
  #pragma unroll
  for (int i = 0; i < 8; ++i)
    asm volatile("global_load_dwordx4 %0, %1, off sc0 sc1"
                 : "=&v"(v[i]) : "v"(s + tid + (i << 8)));
}

// issue 8 PIPELINED plain cached 16B loads (x16 prefetch; pinned issue point)
__device__ __forceinline__ void issue_x8(u32x4* v, const _Float16* __restrict__ src, int tid) {
  const u32x4* s = (const u32x4*)src;
  #pragma unroll
  for (int i = 0; i < 8; ++i)
    asm volatile("global_load_dwordx4 %0, %1, off"
                 : "=&v"(v[i]) : "v"(s + tid + (i << 8)));
}

// single full drain + scheduling fence (rule #18)
__device__ __forceinline__ void wait_vm0() {
  asm volatile("s_waitcnt vmcnt(0)" ::: "memory");
  __builtin_amdgcn_sched_barrier(0);
}

// write registers -> LDS fp16 [MB][KP], XOR-swizzled (16B units)
__device__ __forceinline__ void write_h8(char* st, const u32x4* v, int tid) {
  #pragma unroll
  for (int i = 0; i < 8; ++i) {
    int c  = tid + (i << 8);
    int m  = c >> 6;
    int kc = c & 63;
    int byte = (m * 1024 + (kc << 4)) ^ ((m & 7) << 4);
    *(u32x4*)(st + byte) = v[i];
  }
}

// K-split gemm: wave covers K-slice [kh*256, kh*256+256) for its 2 gates; M=32.
__device__ __forceinline__ void gemm_tile2(f4 (*acc)[2], const char* sm,
                                           const h8 wf[2][8], int col, int krow, int kh) {
  #pragma unroll
  for (int ks = 0; ks < 8; ++ks) {
    #pragma unroll
    for (int mt = 0; mt < 2; ++mt) {
      int lin = mt * 16384 + col * 1024 + (kh * 8 + ks) * 64 + krow * 16;
      h8 af = *(const h8*)(sm + (lin ^ ((col & 7) << 4)));
      acc[0][mt] = __builtin_amdgcn_mfma_f32_16x16x32_f16(af, wf[0][ks], acc[0][mt], 0, 0, 0);
      acc[1][mt] = __builtin_amdgcn_mfma_f32_16x16x32_f16(af, wf[1][ks], acc[1][mt], 0, 0, 0);
    }
  }
}

// wave-0-only poll over spread flag slots, per-lane exit, light backoff;
// barrier releases the other waves. (agent-scope: L3 coherence point — REQUIRED)
__device__ __forceinline__ void poll_sync(const int* fl, int thr_lo, int thr_hi, int tid) {
  if (tid < 64) {
    const int thr = (tid < 32) ? thr_lo : thr_hi;
    const int* p = fl + tid * FSTRIDE;
    while (__hip_atomic_load(p, __ATOMIC_RELAXED, __HIP_MEMORY_SCOPE_AGENT) < thr)
      __builtin_amdgcn_s_sleep(1);
  }
  __syncthreads();
}

__launch_bounds__(256, 2)
__global__ void lstm_kernel(
    const float* __restrict__ x, const _Float16* __restrict__ x16,
    const float* __restrict__ w_ih1, const float* __restrict__ w_hh1,
    const float* __restrict__ b_ih1, const float* __restrict__ b_hh1,
    const float* __restrict__ w_ih2, const float* __restrict__ w_hh2,
    const float* __restrict__ b_ih2, const float* __restrict__ b_hh2,
    const float* __restrict__ w_lin,
    float* __restrict__ out, char* __restrict__ ws)
{
  __shared__ __align__(16) char smem[MB * KP * 2];     // 32 KiB operand stage
  __shared__ __align__(16) float part[2][4][16][36];   // [kh][gate][col][row+pad] 18.4 KiB

  int* flags   = (int*)ws;                                        // [NCH][64][FSTRIDE]
  _Float16* h1 = (_Float16*)(ws + WS_H1_OFF);                     // [R1][B_SZ][KP]
  _Float16* h2 = (_Float16*)(ws + WS_H2_OFF);                     // [R2][B_SZ][KP]

  const int tid  = threadIdx.x;
  const int lane = tid & 63;
  const int wave = tid >> 6;
  const int gp   = wave & 1;           // gate pair: gates {2gp, 2gp+1}
  const int kh   = wave >> 1;          // K-half: [kh*256, kh*256+256)
  const int wg   = blockIdx.x;
  // CO-SCHEDULING DECODE: CU c hosts wg=c (L1) and wg=c+256 (L2) of the SAME
  // chunk — phase-offset layers overlap. All sync stays agent-scope (L3).
  const int mb    = wg & 7;            // chunk 0..7 (spread across XCDs)
  const bool isL2 = (wg >> 8) != 0;    // first 256 WGs = L1, second 256 = L2
  const int nb    = (wg >> 3) & 31;    // hidden block 0..31 (16 units)
  int* flags_c    = flags + mb * 64 * FSTRIDE;
  int* my_flag    = flags + (mb * 64 + (isL2 ? 32 : 0) + nb) * FSTRIDE;

  const int j0   = nb << 4;
  const int col  = lane & 15;
  const int krow = lane >> 4;
  const int jj   = j0 + col;
  const bool jvalid = (jj < F_DIM);

  const float* wA = isL2 ? w_ih2 : w_ih1;
  const float* wB = isL2 ? w_hh2 : w_hh1;
  const float* bi = isL2 ? b_ih2 : b_ih1;
  const float* bh = isL2 ? b_hh2 : b_hh1;

  // B-fragments: 2 gates x K-half per wave, both matrices
  h8 wfA[2][8], wfB[2][8];
  float bias2[2];
  #pragma unroll
  for (int gl = 0; gl < 2; ++gl) {
    const int g    = gp * 2 + gl;
    const int nrow = g * F_DIM + jj;
    #pragma unroll
    for (int ks = 0; ks < 8; ++ks) {
      h8 a, b;
      #pragma unroll
      for (int e = 0; e < 8; ++e) {
        int k = ((kh * 8 + ks) << 5) + (krow << 3) + e;
        bool ok = jvalid && (k < F_DIM);
        a[e] = (_Float16)(ok ? wA[nrow * F_DIM + k] : 0.0f);
        b[e] = (_Float16)(ok ? wB[nrow * F_DIM + k] : 0.0f);
      }
      wfA[gl][ks] = a; wfB[gl][ks] = b;
    }
    bias2[gl] = (kh == 0 && jvalid) ? (bi[nrow] + bh[nrow]) : 0.0f;
  }

  // cell-update mapping: thread owns (row = tid>>3, cols j0 + (tid&7)*2 .. +1)
  const int urow = tid >> 3;           // 0..31
  const int q    = tid & 7;
  float wl2[2];
  #pragma unroll
  for (int cc = 0; cc < 2; ++cc) {
    int j = j0 + (q << 1) + cc;
    wl2[cc] = (isL2 && j < F_DIM) ? w_lin[j] : 0.0f;
  }

  float cst[2] = {0.f, 0.f};
  f4 acc[2][2];

  if (!isL2) {
    // ================= Layer-1 pipeline =================
    u32x4 hstg[8], xstg[8];
    if (x16) stage_x16(smem, x16 + ((size_t)0 * B_SZ + mb * MB) * KP, tid);
    else     stage_x  (smem, x + (size_t)mb * MB * F_DIM, tid);
    __syncthreads();

    for (int t = 0; t < T_ST; ++t) {
      #pragma unroll
      for (int gl = 0; gl < 2; ++gl)
        #pragma unroll
        for (int mt = 0; mt < 2; ++mt)
          acc[gl][mt] = (f4){bias2[gl], bias2[gl], bias2[gl], bias2[gl]};

      const bool pf = x16 && (t + 1 < T_ST);
      if (t > 0) {
        // chain: poll -> issue h1(t-1) + x(t+1) -> gemm1 (hides RTs) -> LDS -> gemm2
        poll_sync(flags_c, t, t - 7, tid);
        issue_h8(hstg, h1 + ((size_t)((t - 1) % R1) * B_SZ + mb * MB) * KP, tid);
        if (pf) issue_x8(xstg, x16 + ((size_t)(t + 1) * B_SZ + mb * MB) * KP, tid);
        gemm_tile2(acc, smem, wfA, col, krow, kh);   // x(t) path
        __syncthreads();             // gemm1 smem readers done
        wait_vm0();                  // drains h1 AND x-prefetch together
        write_h8(smem, hstg, tid);
        __syncthreads();
        gemm_tile2(acc, smem, wfB, col, krow, kh);   // h path
      } else {
        if (pf) issue_x8(xstg, x16 + ((size_t)(t + 1) * B_SZ + mb * MB) * KP, tid);
        gemm_tile2(acc, smem, wfA, col, krow, kh);
        wait_vm0();
      }

      // publish partials
      #pragma unroll
      for (int gl = 0; gl < 2; ++gl)
        #pragma unroll
        for (int mt = 0; mt < 2; ++mt)
          *(f4*)&part[kh][gp * 2 + gl][col][mt * 16 + (krow << 2)] = acc[gl][mt];
      __syncthreads();

      // cell update + h1 store
      float hv[2];
      #pragma unroll
      for (int cc = 0; cc < 2; ++cc) {
        int lc = (q << 1) + cc;
        float gi = part[0][0][lc][urow] + part[1][0][lc][urow];
        float gf = part[0][1][lc][urow] + part[1][1][lc][urow];
        float gg = part[0][2][lc][urow] + part[1][2][lc][urow];
        float go = part[0][3][lc][urow] + part[1][3][lc][urow];
        float cn = sigm(gf) * cst[cc] + sigm(gi) * tanh_f(gg);
        cst[cc] = cn;
        hv[cc] = sigm(go) * tanh_f(cn);
      }
      unsigned int hb;
      {
        unsigned int s0 = __builtin_bit_cast(unsigned short, (_Float16)hv[0]);
        unsigned int s1 = __builtin_bit_cast(unsigned short, (_Float16)hv[1]);
        hb = s0 | (s1 << 16);
      }
      int bg = mb * MB + urow;
      {
        char* dst = (char*)(h1 + (size_t)(t % R1) * B_SZ * KP +
                            (size_t)bg * KP + j0 + (q << 1));
        asm volatile("global_store_dword %0, %1, off sc0 sc1"
                     :: "v"(dst), "v"(hb) : "memory");
      }
      asm volatile("s_waitcnt vmcnt(0)" ::: "memory");
      __syncthreads();
      if (tid == 0)
        __hip_atomic_store(my_flag, t + 1,
                           __ATOMIC_RELAXED, __HIP_MEMORY_SCOPE_AGENT);

      // tail (off-chain): LDS-only write of prefetched x(t+1)
      if (t + 1 < T_ST) {
        if (x16) write_h8(smem, xstg, tid);
        else     stage_x(smem, x + ((size_t)(t + 1) * B_SZ + mb * MB) * F_DIM, tid);
        // next-iteration poll_sync barrier orders these writes vs gemm1 reads
      }
    }
  } else {
    // ================= Layer-2 pipeline =================
    u32x4 hstg[8], hstg2[8];
    for (int t = 0; t < T_ST; ++t) {
      #pragma unroll
      for (int gl = 0; gl < 2; ++gl)
        #pragma unroll
        for (int mt = 0; mt < 2; ++mt)
          acc[gl][mt] = (f4){bias2[gl], bias2[gl], bias2[gl], bias2[gl]};

      // need: L1 done step t (flag>=t+1); L2 peers done step t-1 (flag>=t)
      poll_sync(flags_c, t + 1, t, tid);
      // issue BOTH tiles back-to-back; single drain (one exposed RT total)
      if (t > 0) issue_h8(hstg2, h2 + ((size_t)((t - 1) % R2) * B_SZ + mb * MB) * KP, tid);
      issue_h8(hstg, h1 + ((size_t)(t % R1) * B_SZ + mb * MB) * KP, tid);
      wait_vm0();
      if (t > 0) {
        write_h8(smem, hstg2, tid);  // prev-iter readers joined at poll barrier
        __syncthreads();
        gemm_tile2(acc, smem, wfB, col, krow, kh);   // h2 path first
        __syncthreads();             // gemm readers done before restage
      }
      write_h8(smem, hstg, tid);
      __syncthreads();
      gemm_tile2(acc, smem, wfA, col, krow, kh);     // h1 path

      // publish partials
      #pragma unroll
      for (int gl = 0; gl < 2; ++gl)
        #pragma unroll
        for (int mt = 0; mt < 2; ++mt)
          *(f4*)&part[kh][gp * 2 + gl][col][mt * 16 + (krow << 2)] = acc[gl][mt];
      __syncthreads();

      // cell update + h2 store
      float hv[2];
      #pragma unroll
      for (int cc = 0; cc < 2; ++cc) {
        int lc = (q << 1) + cc;
        float gi = part[0][0][lc][urow] + part[1][0][lc][urow];
        float gf = part[0][1][lc][urow] + part[1][1][lc][urow];
        float gg = part[0][2][lc][urow] + part[1][2][lc][urow];
        float go = part[0][3][lc][urow] + part[1][3][lc][urow];
        float cn = sigm(gf) * cst[cc] + sigm(gi) * tanh_f(gg);
        cst[cc] = cn;
        hv[cc] = sigm(go) * tanh_f(cn);
      }
      unsigned int hb;
      {
        unsigned int s0 = __builtin_bit_cast(unsigned short, (_Float16)hv[0]);
        unsigned int s1 = __builtin_bit_cast(unsigned short, (_Float16)hv[1]);
        hb = s0 | (s1 << 16);
      }
      int bg = mb * MB + urow;
      {
        char* dst = (char*)(h2 + (size_t)(t % R2) * B_SZ * KP +
                            (size_t)bg * KP + j0 + (q << 1));
        asm volatile("global_store_dword %0, %1, off sc0 sc1"
                     :: "v"(dst), "v"(hb) : "memory");
      }
      asm volatile("s_waitcnt vmcnt(0)" ::: "memory");
      __syncthreads();
      if (tid == 0)
        __hip_atomic_store(my_flag, t + 1,
                           __ATOMIC_RELAXED, __HIP_MEMORY_SCOPE_AGENT);

      // contended output atomics AFTER the flag -> off the critical path
      float py = hv[0] * wl2[0] + hv[1] * wl2[1];
      py += __shfl_xor(py, 1);
      py += __shfl_xor(py, 2);
      py += __shfl_xor(py, 4);
      if (q == 0) atomicAdd(out + (size_t)bg * T_ST + t, py);
    }
  }
}

extern "C" void kernel_launch(void* const* d_in, const int* in_sizes, int n_in,
                              void* d_out, int out_size, void* d_ws, size_t ws_size,
                              hipStream_t stream) {
  (void)in_sizes; (void)n_in; (void)out_size;
  const float* x     = (const float*)d_in[0];
  const float* w_ih1 = (const float*)d_in[1];
  const float* w_hh1 = (const float*)d_in[2];
  const float* b_ih1 = (const float*)d_in[3];
  const float* b_hh1 = (const float*)d_in[4];
  const float* w_ih2 = (const float*)d_in[5];
  const float* w_hh2 = (const float*)d_in[6];
  const float* b_ih2 = (const float*)d_in[7];
  const float* b_hh2 = (const float*)d_in[8];
  const float* w_lin = (const float*)d_in[9];
  const float* b_lin = (const float*)d_in[10];
  float* out = (float*)d_out;
  char* ws   = (char*)d_ws;

  const bool have_x16 = ws_size >= WS_X16_OFF + X16_BYTES;
  _Float16* x16 = have_x16 ? (_Float16*)(ws + WS_X16_OFF) : nullptr;

  hipLaunchKernelGGL(init_kernel, dim3((B_SZ * T_ST + 255) / 256), dim3(256), 0, stream,
                     out, b_lin, (int*)ws);
  if (have_x16) {
    const int total_thr = T_ST * B_SZ * 64;   // 8 elems per thread
    hipLaunchKernelGGL(cvt_x_kernel, dim3(total_thr / 256), dim3(256), 0, stream,
                       x, x16);
  }
  hipLaunchKernelGGL(lstm_kernel, dim3(NWG), dim3(256), 0, stream,
                     x, x16, w_ih1, w_hh1, b_ih1, b_hh1,
                     w_ih2, w_hh2, b_ih2, b_hh2,
                     w_lin, out, ws);
}

// Round 19
// 3774.885 us; speedup vs baseline: 1.4710x; 1.4710x over previous
//
#include <hip/hip_runtime.h>
#include <hip/hip_fp16.h>

#define F_DIM 510
#define KP    512      // padded K
#define B_SZ  256
#define T_ST  512
#define MB    32       // batch rows per chunk (8 chunks)
#define NCH   8
#define NWG   512      // 2 WGs per CU
#define R1    8        // h1 ring depth
#define R2    4        // h2 ring depth
#define FSTRIDE 32     // ints per flag slot (128B; de-hotspot slices)

#define WS_FLAGS_BYTES ((size_t)NCH * 64 * FSTRIDE * 4)   // 64 KiB
#define WS_H1_OFF  WS_FLAGS_BYTES
#define WS_H2_OFF  (WS_H1_OFF + (size_t)R1 * B_SZ * KP * 2)
#define WS_X16_OFF (WS_H2_OFF + (size_t)R2 * B_SZ * KP * 2)
#define X16_BYTES  ((size_t)T_ST * B_SZ * KP * 2)

typedef _Float16 h8 __attribute__((ext_vector_type(8)));
typedef float    f4 __attribute__((ext_vector_type(4)));
typedef unsigned int u32x4 __attribute__((ext_vector_type(4)));
typedef unsigned long long u64;

__device__ __forceinline__ float sigm(float v)   { return 1.0f / (1.0f + __expf(-v)); }
__device__ __forceinline__ float tanh_f(float v) { return 1.0f - 2.0f / (__expf(2.0f * v) + 1.0f); }

__global__ void init_kernel(float* __restrict__ out, const float* __restrict__ b_lin,
                            int* __restrict__ flags) {
  int i = blockIdx.x * blockDim.x + threadIdx.x;
  if (i < NCH * 64 * FSTRIDE) flags[i] = 0;
  if (i < B_SZ * T_ST) out[i] = b_lin[0];
}

// pre-pass: x fp32 [T*B][F_DIM] -> fp16 [T*B][KP] (zero-padded)
__global__ void cvt_x_kernel(const float* __restrict__ x, _Float16* __restrict__ x16) {
  size_t i = (size_t)blockIdx.x * blockDim.x + threadIdx.x;   // 0 .. T*B*64-1
  int g = (int)(i & 63);
  size_t s = i >> 6;
  int k0 = g << 3;
  const float* src = x + s * F_DIM + k0;
  h8 v;
  if (k0 + 8 <= F_DIM) {
    #pragma unroll
    for (int e = 0; e < 4; ++e) {
      float2 p = *(const float2*)(src + 2 * e);
      v[2 * e]     = (_Float16)p.x;
      v[2 * e + 1] = (_Float16)p.y;
    }
  } else {
    #pragma unroll
    for (int e = 0; e < 8; ++e) v[e] = (_Float16)((k0 + e < F_DIM) ? src[e] : 0.0f);
  }
  *(h8*)(x16 + s * KP + k0) = v;
}

// stage fp32 x [MB][F_DIM] -> LDS fp16 [MB][KP], XOR-swizzled (fallback path)
__device__ __forceinline__ void stage_x(char* st, const float* __restrict__ src, int tid) {
  #pragma unroll
  for (int i = 0; i < 8; ++i) {
    int c  = tid + (i << 8);
    int m  = c >> 6;
    int kb = (c & 63) << 3;
    h8 v;
    const float* s = src + m * F_DIM + kb;
    if (kb + 8 <= F_DIM) {
      #pragma unroll
      for (int e = 0; e < 4; ++e) {
        float2 p = *(const float2*)(s + 2 * e);
        v[2 * e]     = (_Float16)p.x;
        v[2 * e + 1] = (_Float16)p.y;
      }
    } else {
      #pragma unroll
      for (int e = 0; e < 8; ++e) v[e] = (_Float16)((kb + e < F_DIM) ? s[e] : 0.0f);
    }
    int byte = ((m * KP + kb) << 1) ^ ((m & 7) << 4);
    *(h8*)(st + byte) = v;
  }
}

// stage fp16 x16 [MB][KP] -> LDS, XOR-swizzled (plain cached loads; split issue/use)
__device__ __forceinline__ void stage_x16(char* st, const _Float16* __restrict__ src, int tid) {
  u32x4 v[8];
  const u32x4* s = (const u32x4*)src;
  #pragma unroll
  for (int i = 0; i < 8; ++i) v[i] = s[tid + (i << 8)];
  #pragma unroll
  for (int i = 0; i < 8; ++i) {
    int c  = tid + (i << 8);
    int m  = c >> 6;
    int kc = c & 63;
    int byte = (m * 1024 + (kc << 4)) ^ ((m & 7) << 4);
    *(u32x4*)(st + byte) = v[i];
  }
}

// issue 8 PIPELINED coherent 16B loads (32 KiB tile / 256 threads)
__device__ __forceinline__ void issue_h8(u32x4* v, const _Float16* __restrict__ src, int tid) {
  const u32x4* s = (const u32x4*)src;
  #pragma unroll
  for (int i = 0; i < 8; ++i)
    asm volatile("global_load_dwordx4 %0, %1, off sc0 sc1"
                 : "=&v"(v[i]) : "v"(s + tid + (i << 8)));
}

// issue 8 PIPELINED plain cached 16B loads (x16 prefetch; reuses a dead array)
__device__ __forceinline__ void issue_x8(u32x4* v, const _Float16* __restrict__ src, int tid) {
  const u32x4* s = (const u32x4*)src;
  #pragma unroll
  for (int i = 0; i < 8; ++i)
    asm volatile("global_load_dwordx4 %0, %1, off"
                 : "=&v"(v[i]) : "v"(s + tid + (i << 8)));
}

// single full drain + scheduling fence (rule #18)
__device__ __forceinline__ void wait_vm0() {
  asm volatile("s_waitcnt vmcnt(0)" ::: "memory");
  __builtin_amdgcn_sched_barrier(0);
}

// write registers -> LDS fp16 [MB][KP], XOR-swizzled (16B units)
__device__ __forceinline__ void write_h8(char* st, const u32x4* v, int tid) {
  #pragma unroll
  for (int i = 0; i < 8; ++i) {
    int c  = tid + (i << 8);
    int m  = c >> 6;
    int kc = c & 63;
    int byte = (m * 1024 + (kc << 4)) ^ ((m & 7) << 4);
    *(u32x4*)(st + byte) = v[i];
  }
}

// K-split gemm: wave covers K-slice [kh*256, kh*256+256) for its 2 gates; M=32.
__device__ __forceinline__ void gemm_tile2(f4 (*acc)[2], const char* sm,
                                           const h8 wf[2][8], int col, int krow, int kh) {
  #pragma unroll
  for (int ks = 0; ks < 8; ++ks) {
    #pragma unroll
    for (int mt = 0; mt < 2; ++mt) {
      int lin = mt * 16384 + col * 1024 + (kh * 8 + ks) * 64 + krow * 16;
      h8 af = *(const h8*)(sm + (lin ^ ((col & 7) << 4)));
      acc[0][mt] = __builtin_amdgcn_mfma_f32_16x16x32_f16(af, wf[0][ks], acc[0][mt], 0, 0, 0);
      acc[1][mt] = __builtin_amdgcn_mfma_f32_16x16x32_f16(af, wf[1][ks], acc[1][mt], 0, 0, 0);
    }
  }
}

// wave-0-only poll over spread flag slots, per-lane exit, sleep between probes;
// barrier releases the other waves. (agent-scope: L3 coherence point — REQUIRED)
__device__ __forceinline__ void poll_sync(const int* fl, int thr_lo, int thr_hi, int tid) {
  if (tid < 64) {
    const int thr = (tid < 32) ? thr_lo : thr_hi;
    const int* p = fl + tid * FSTRIDE;
    while (__hip_atomic_load(p, __ATOMIC_RELAXED, __HIP_MEMORY_SCOPE_AGENT) < thr)
      __builtin_amdgcn_s_sleep(2);
  }
  __syncthreads();
}

__launch_bounds__(256, 2)
__global__ void lstm_kernel(
    const float* __restrict__ x, const _Float16* __restrict__ x16,
    const float* __restrict__ w_ih1, const float* __restrict__ w_hh1,
    const float* __restrict__ b_ih1, const float* __restrict__ b_hh1,
    const float* __restrict__ w_ih2, const float* __restrict__ w_hh2,
    const float* __restrict__ b_ih2, const float* __restrict__ b_hh2,
    const float* __restrict__ w_lin,
    float* __restrict__ out, char* __restrict__ ws)
{
  __shared__ __align__(16) char smem[MB * KP * 2];     // 32 KiB operand stage
  __shared__ __align__(16) float part[2][4][16][36];   // [kh][gate][col][row+pad] 18.4 KiB

  int* flags   = (int*)ws;                                        // [NCH][64][FSTRIDE]
  _Float16* h1 = (_Float16*)(ws + WS_H1_OFF);                     // [R1][B_SZ][KP]
  _Float16* h2 = (_Float16*)(ws + WS_H2_OFF);                     // [R2][B_SZ][KP]

  const int tid  = threadIdx.x;
  const int lane = tid & 63;
  const int wave = tid >> 6;
  const int gp   = wave & 1;           // gate pair: gates {2gp, 2gp+1}
  const int kh   = wave >> 1;          // K-half: [kh*256, kh*256+256)
  const int wg   = blockIdx.x;
  // CO-SCHEDULING DECODE: CU c hosts wg=c (L1) and wg=c+256 (L2) of the SAME
  // chunk — phase-offset layers overlap. All sync stays agent-scope (L3).
  const int mb    = wg & 7;            // chunk 0..7 (spread across XCDs)
  const bool isL2 = (wg >> 8) != 0;    // first 256 WGs = L1, second 256 = L2
  const int nb    = (wg >> 3) & 31;    // hidden block 0..31 (16 units)
  int* flags_c    = flags + mb * 64 * FSTRIDE;
  int* my_flag    = flags + (mb * 64 + (isL2 ? 32 : 0) + nb) * FSTRIDE;

  const int j0   = nb << 4;
  const int col  = lane & 15;
  const int krow = lane >> 4;
  const int jj   = j0 + col;
  const bool jvalid = (jj < F_DIM);

  const float* wA = isL2 ? w_ih2 : w_ih1;
  const float* wB = isL2 ? w_hh2 : w_hh1;
  const float* bi = isL2 ? b_ih2 : b_ih1;
  const float* bh = isL2 ? b_hh2 : b_hh1;

  // B-fragments: 2 gates x K-half per wave, both matrices
  h8 wfA[2][8], wfB[2][8];
  float bias2[2];
  #pragma unroll
  for (int gl = 0; gl < 2; ++gl) {
    const int g    = gp * 2 + gl;
    const int nrow = g * F_DIM + jj;
    #pragma unroll
    for (int ks = 0; ks < 8; ++ks) {
      h8 a, b;
      #pragma unroll
      for (int e = 0; e < 8; ++e) {
        int k = ((kh * 8 + ks) << 5) + (krow << 3) + e;
        bool ok = jvalid && (k < F_DIM);
        a[e] = (_Float16)(ok ? wA[nrow * F_DIM + k] : 0.0f);
        b[e] = (_Float16)(ok ? wB[nrow * F_DIM + k] : 0.0f);
      }
      wfA[gl][ks] = a; wfB[gl][ks] = b;
    }
    bias2[gl] = (kh == 0 && jvalid) ? (bi[nrow] + bh[nrow]) : 0.0f;
  }

  // cell-update mapping: thread owns (row = tid>>3, cols j0 + (tid&7)*2 .. +1)
  const int urow = tid >> 3;           // 0..31
  const int q    = tid & 7;
  float wl2[2];
  #pragma unroll
  for (int cc = 0; cc < 2; ++cc) {
    int j = j0 + (q << 1) + cc;
    wl2[cc] = (isL2 && j < F_DIM) ? w_lin[j] : 0.0f;
  }

  float cst[2] = {0.f, 0.f};
  u32x4 hstg[8];
  f4 acc[2][2];

  if (!isL2) {
    // ================= Layer-1 pipeline =================
    if (x16) stage_x16(smem, x16 + ((size_t)0 * B_SZ + mb * MB) * KP, tid);
    else     stage_x  (smem, x + (size_t)mb * MB * F_DIM, tid);
    __syncthreads();

    for (int t = 0; t < T_ST; ++t) {
      #pragma unroll
      for (int gl = 0; gl < 2; ++gl)
        #pragma unroll
        for (int mt = 0; mt < 2; ++mt)
          acc[gl][mt] = (f4){bias2[gl], bias2[gl], bias2[gl], bias2[gl]};

      if (t > 0) {
        // chain: poll -> issue h1(t-1) -> gemm1 (hides h latency) -> LDS -> gemm2
        poll_sync(flags_c, t, t - 7, tid);
        issue_h8(hstg, h1 + ((size_t)((t - 1) % R1) * B_SZ + mb * MB) * KP, tid);
        gemm_tile2(acc, smem, wfA, col, krow, kh);   // x(t) path
        __syncthreads();             // gemm1 smem readers done
        wait_vm0();
        write_h8(smem, hstg, tid);   // hstg live range ENDS here
        __syncthreads();
        gemm_tile2(acc, smem, wfB, col, krow, kh);   // h path
      } else {
        gemm_tile2(acc, smem, wfA, col, krow, kh);
      }

      // publish partials
      #pragma unroll
      for (int gl = 0; gl < 2; ++gl)
        #pragma unroll
        for (int mt = 0; mt < 2; ++mt)
          *(f4*)&part[kh][gp * 2 + gl][col][mt * 16 + (krow << 2)] = acc[gl][mt];
      __syncthreads();

      // x(t+1) prefetch into hstg (dead regs — zero extra pressure); drains
      // under the h-store vmcnt(0) below, tail becomes LDS-only.
      const bool pf = x16 && (t + 1 < T_ST);
      if (pf) issue_x8(hstg, x16 + ((size_t)(t + 1) * B_SZ + mb * MB) * KP, tid);

      // cell update + h1 store
      float hv[2];
      #pragma unroll
      for (int cc = 0; cc < 2; ++cc) {
        int lc = (q << 1) + cc;
        float gi = part[0][0][lc][urow] + part[1][0][lc][urow];
        float gf = part[0][1][lc][urow] + part[1][1][lc][urow];
        float gg = part[0][2][lc][urow] + part[1][2][lc][urow];
        float go = part[0][3][lc][urow] + part[1][3][lc][urow];
        float cn = sigm(gf) * cst[cc] + sigm(gi) * tanh_f(gg);
        cst[cc] = cn;
        hv[cc] = sigm(go) * tanh_f(cn);
      }
      unsigned int hb;
      {
        unsigned int s0 = __builtin_bit_cast(unsigned short, (_Float16)hv[0]);
        unsigned int s1 = __builtin_bit_cast(unsigned short, (_Float16)hv[1]);
        hb = s0 | (s1 << 16);
      }
      int bg = mb * MB + urow;
      {
        char* dst = (char*)(h1 + (size_t)(t % R1) * B_SZ * KP +
                            (size_t)bg * KP + j0 + (q << 1));
        asm volatile("global_store_dword %0, %1, off sc0 sc1"
                     :: "v"(dst), "v"(hb) : "memory");
      }
      asm volatile("s_waitcnt vmcnt(0)" ::: "memory");   // drains store + x-prefetch
      __syncthreads();
      if (tid == 0)
        __hip_atomic_store(my_flag, t + 1,
                           __ATOMIC_RELAXED, __HIP_MEMORY_SCOPE_AGENT);

      // tail (off-chain): LDS-only write of prefetched x(t+1)
      if (t + 1 < T_ST) {
        if (x16) write_h8(smem, hstg, tid);
        else     stage_x(smem, x + ((size_t)(t + 1) * B_SZ + mb * MB) * F_DIM, tid);
        // next-iteration poll_sync barrier orders these writes vs gemm1 reads
      }
    }
  } else {
    // ================= Layer-2 pipeline =================
    for (int t = 0; t < T_ST; ++t) {
      #pragma unroll
      for (int gl = 0; gl < 2; ++gl)
        #pragma unroll
        for (int mt = 0; mt < 2; ++mt)
          acc[gl][mt] = (f4){bias2[gl], bias2[gl], bias2[gl], bias2[gl]};

      // need: L1 done step t (flag>=t+1); L2 peers done step t-1 (flag>=t)
      poll_sync(flags_c, t + 1, t, tid);
      issue_h8(hstg, h1 + ((size_t)(t % R1) * B_SZ + mb * MB) * KP, tid);
      wait_vm0();
      write_h8(smem, hstg, tid);     // prev-iter readers joined at poll barrier
      __syncthreads();
      if (t > 0)                     // h2(t-1) loads; latency hides under GEMM1
        issue_h8(hstg, h2 + ((size_t)((t - 1) % R2) * B_SZ + mb * MB) * KP, tid);
      gemm_tile2(acc, smem, wfA, col, krow, kh);
      if (t > 0) {
        __syncthreads();             // gemm1 readers done
        wait_vm0();
        write_h8(smem, hstg, tid);
        __syncthreads();
        gemm_tile2(acc, smem, wfB, col, krow, kh);
      }

      // publish partials
      #pragma unroll
      for (int gl = 0; gl < 2; ++gl)
        #pragma unroll
        for (int mt = 0; mt < 2; ++mt)
          *(f4*)&part[kh][gp * 2 + gl][col][mt * 16 + (krow << 2)] = acc[gl][mt];
      __syncthreads();

      // cell update + h2 store
      float hv[2];
      #pragma unroll
      for (int cc = 0; cc < 2; ++cc) {
        int lc = (q << 1) + cc;
        float gi = part[0][0][lc][urow] + part[1][0][lc][urow];
        float gf = part[0][1][lc][urow] + part[1][1][lc][urow];
        float gg = part[0][2][lc][urow] + part[1][2][lc][urow];
        float go = part[0][3][lc][urow] + part[1][3][lc][urow];
        float cn = sigm(gf) * cst[cc] + sigm(gi) * tanh_f(gg);
        cst[cc] = cn;
        hv[cc] = sigm(go) * tanh_f(cn);
      }
      unsigned int hb;
      {
        unsigned int s0 = __builtin_bit_cast(unsigned short, (_Float16)hv[0]);
        unsigned int s1 = __builtin_bit_cast(unsigned short, (_Float16)hv[1]);
        hb = s0 | (s1 << 16);
      }
      int bg = mb * MB + urow;
      {
        char* dst = (char*)(h2 + (size_t)(t % R2) * B_SZ * KP +
                            (size_t)bg * KP + j0 + (q << 1));
        asm volatile("global_store_dword %0, %1, off sc0 sc1"
                     :: "v"(dst), "v"(hb) : "memory");
      }
      asm volatile("s_waitcnt vmcnt(0)" ::: "memory");
      __syncthreads();
      if (tid == 0)
        __hip_atomic_store(my_flag, t + 1,
                           __ATOMIC_RELAXED, __HIP_MEMORY_SCOPE_AGENT);

      // contended output atomics AFTER the flag -> off the critical path
      float py = hv[0] * wl2[0] + hv[1] * wl2[1];
      py += __shfl_xor(py, 1);
      py += __shfl_xor(py, 2);
      py += __shfl_xor(py, 4);
      if (q == 0) atomicAdd(out + (size_t)bg * T_ST + t, py);
    }
  }
}

extern "C" void kernel_launch(void* const* d_in, const int* in_sizes, int n_in,
                              void* d_out, int out_size, void* d_ws, size_t ws_size,
                              hipStream_t stream) {
  (void)in_sizes; (void)n_in; (void)out_size;
  const float* x     = (const float*)d_in[0];
  const float* w_ih1 = (const float*)d_in[1];
  const float* w_hh1 = (const float*)d_in[2];
  const float* b_ih1 = (const float*)d_in[3];
  const float* b_hh1 = (const float*)d_in[4];
  const float* w_ih2 = (const float*)d_in[5];
  const float* w_hh2 = (const float*)d_in[6];
  const float* b_ih2 = (const float*)d_in[7];
  const float* b_hh2 = (const float*)d_in[8];
  const float* w_lin = (const float*)d_in[9];
  const float* b_lin = (const float*)d_in[10];
  float* out = (float*)d_out;
  char* ws   = (char*)d_ws;

  const bool have_x16 = ws_size >= WS_X16_OFF + X16_BYTES;
  _Float16* x16 = have_x16 ? (_Float16*)(ws + WS_X16_OFF) : nullptr;

  hipLaunchKernelGGL(init_kernel, dim3((B_SZ * T_ST + 255) / 256), dim3(256), 0, stream,
                     out, b_lin, (int*)ws);
  if (have_x16) {
    const int total_thr = T_ST * B_SZ * 64;   // 8 elems per thread
    hipLaunchKernelGGL(cvt_x_kernel, dim3(total_thr / 256), dim3(256), 0, stream,
                       x, x16);
  }
  hipLaunchKernelGGL(lstm_kernel, dim3(NWG), dim3(256), 0, stream,
                     x, x16, w_ih1, w_hh1, b_ih1, b_hh1,
                     w_ih2, w_hh2, b_ih2, b_hh2,
                     w_lin, out, ws);
}

// Round 20
// 3325.950 us; speedup vs baseline: 1.6695x; 1.1350x over previous
//
#include <hip/hip_runtime.h>
#include <hip/hip_fp16.h>

#define F_DIM 510
#define KP    512      // padded K
#define B_SZ  256
#define T_ST  512
#define MB    32       // batch rows per chunk (8 chunks)
#define NCH   8
#define NWG   512      // 2 WGs per CU
#define R1    8        // h1 ring depth
#define R2    4        // h2 ring depth
#define FSTRIDE 32     // ints per flag slot (128B; de-hotspot slices)

#define WS_FLAGS_BYTES ((size_t)NCH * 64 * FSTRIDE * 4)   // 64 KiB
#define WS_H1_OFF  WS_FLAGS_BYTES
#define WS_H2_OFF  (WS_H1_OFF + (size_t)R1 * B_SZ * KP * 2)
#define WS_X16_OFF (WS_H2_OFF + (size_t)R2 * B_SZ * KP * 2)
#define X16_BYTES  ((size_t)T_ST * B_SZ * KP * 2)

typedef _Float16 h8 __attribute__((ext_vector_type(8)));
typedef float    f4 __attribute__((ext_vector_type(4)));
typedef unsigned int u32x4 __attribute__((ext_vector_type(4)));
typedef unsigned long long u64;

__device__ __forceinline__ float sigm(float v)   { return 1.0f / (1.0f + __expf(-v)); }
__device__ __forceinline__ float tanh_f(float v) { return 1.0f - 2.0f / (__expf(2.0f * v) + 1.0f); }

__global__ void init_kernel(float* __restrict__ out, const float* __restrict__ b_lin,
                            int* __restrict__ flags) {
  int i = blockIdx.x * blockDim.x + threadIdx.x;
  if (i < NCH * 64 * FSTRIDE) flags[i] = 0;
  if (i < B_SZ * T_ST) out[i] = b_lin[0];
}

// pre-pass: x fp32 [T*B][F_DIM] -> fp16 [T*B][KP] (zero-padded)
__global__ void cvt_x_kernel(const float* __restrict__ x, _Float16* __restrict__ x16) {
  size_t i = (size_t)blockIdx.x * blockDim.x + threadIdx.x;   // 0 .. T*B*64-1
  int g = (int)(i & 63);
  size_t s = i >> 6;
  int k0 = g << 3;
  const float* src = x + s * F_DIM + k0;
  h8 v;
  if (k0 + 8 <= F_DIM) {
    #pragma unroll
    for (int e = 0; e < 4; ++e) {
      float2 p = *(const float2*)(src + 2 * e);
      v[2 * e]     = (_Float16)p.x;
      v[2 * e + 1] = (_Float16)p.y;
    }
  } else {
    #pragma unroll
    for (int e = 0; e < 8; ++e) v[e] = (_Float16)((k0 + e < F_DIM) ? src[e] : 0.0f);
  }
  *(h8*)(x16 + s * KP + k0) = v;
}

// stage fp32 x [MB][F_DIM] -> LDS fp16 [MB][KP], XOR-swizzled (fallback path)
__device__ __forceinline__ void stage_x(char* st, const float* __restrict__ src, int tid) {
  #pragma unroll
  for (int i = 0; i < 8; ++i) {
    int c  = tid + (i << 8);
    int m  = c >> 6;
    int kb = (c & 63) << 3;
    h8 v;
    const float* s = src + m * F_DIM + kb;
    if (kb + 8 <= F_DIM) {
      #pragma unroll
      for (int e = 0; e < 4; ++e) {
        float2 p = *(const float2*)(s + 2 * e);
        v[2 * e]     = (_Float16)p.x;
        v[2 * e + 1] = (_Float16)p.y;
      }
    } else {
      #pragma unroll
      for (int e = 0; e < 8; ++e) v[e] = (_Float16)((kb + e < F_DIM) ? s[e] : 0.0f);
    }
    int byte = ((m * KP + kb) << 1) ^ ((m & 7) << 4);
    *(h8*)(st + byte) = v;
  }
}

// stage fp16 x16 [MB][KP] -> LDS, XOR-swizzled (plain cached loads; split issue/use)
__device__ __forceinline__ void stage_x16(char* st, const _Float16* __restrict__ src, int tid) {
  u32x4 v[8];
  const u32x4* s = (const u32x4*)src;
  #pragma unroll
  for (int i = 0; i < 8; ++i) v[i] = s[tid + (i << 8)];
  #pragma unroll
  for (int i = 0; i < 8; ++i) {
    int c  = tid + (i << 8);
    int m  = c >> 6;
    int kc = c & 63;
    int byte = (m * 1024 + (kc << 4)) ^ ((m & 7) << 4);
    *(u32x4*)(st + byte) = v[i];
  }
}

// issue 8 PIPELINED coherent 16B loads (32 KiB tile / 256 threads)
__device__ __forceinline__ void issue_h8(u32x4* v, const _Float16* __restrict__ src, int tid) {
  const u32x4* s = (const u32x4*)src;
  #pragma unroll
  for (int i = 0; i < 8; ++i)
    asm volatile("global_load_dwordx4 %0, %1, off sc0 sc1"
                 : "=&v"(v[i]) : "v"(s + tid + (i << 8)));
}

// single full drain + scheduling fence (rule #18)
__device__ __forceinline__ void wait_vm0() {
  asm volatile("s_waitcnt vmcnt(0)" ::: "memory");
  __builtin_amdgcn_sched_barrier(0);
}

// write registers -> LDS fp16 [MB][KP], XOR-swizzled (16B units)
__device__ __forceinline__ void write_h8(char* st, const u32x4* v, int tid) {
  #pragma unroll
  for (int i = 0; i < 8; ++i) {
    int c  = tid + (i << 8);
    int m  = c >> 6;
    int kc = c & 63;
    int byte = (m * 1024 + (kc << 4)) ^ ((m & 7) << 4);
    *(u32x4*)(st + byte) = v[i];
  }
}

// K-split gemm: wave covers K-slice [kh*256, kh*256+256) for its 2 gates; M=32.
__device__ __forceinline__ void gemm_tile2(f4 (*acc)[2], const char* sm,
                                           const h8 wf[2][8], int col, int krow, int kh) {
  #pragma unroll
  for (int ks = 0; ks < 8; ++ks) {
    #pragma unroll
    for (int mt = 0; mt < 2; ++mt) {
      int lin = mt * 16384 + col * 1024 + (kh * 8 + ks) * 64 + krow * 16;
      h8 af = *(const h8*)(sm + (lin ^ ((col & 7) << 4)));
      acc[0][mt] = __builtin_amdgcn_mfma_f32_16x16x32_f16(af, wf[0][ks], acc[0][mt], 0, 0, 0);
      acc[1][mt] = __builtin_amdgcn_mfma_f32_16x16x32_f16(af, wf[1][ks], acc[1][mt], 0, 0, 0);
    }
  }
}

// wave-0-only poll over spread flag slots, per-lane exit, light backoff;
// barrier releases the other waves. (agent-scope: L3 coherence point — REQUIRED)
__device__ __forceinline__ void poll_sync(const int* fl, int thr_lo, int thr_hi, int tid) {
  if (tid < 64) {
    const int thr = (tid < 32) ? thr_lo : thr_hi;
    const int* p = fl + tid * FSTRIDE;
    while (__hip_atomic_load(p, __ATOMIC_RELAXED, __HIP_MEMORY_SCOPE_AGENT) < thr)
      __builtin_amdgcn_s_sleep(1);
  }
  __syncthreads();
}

__launch_bounds__(256, 2)
__global__ void lstm_kernel(
    const float* __restrict__ x, const _Float16* __restrict__ x16,
    const float* __restrict__ w_ih1, const float* __restrict__ w_hh1,
    const float* __restrict__ b_ih1, const float* __restrict__ b_hh1,
    const float* __restrict__ w_ih2, const float* __restrict__ w_hh2,
    const float* __restrict__ b_ih2, const float* __restrict__ b_hh2,
    const float* __restrict__ w_lin,
    float* __restrict__ out, char* __restrict__ ws)
{
  __shared__ __align__(16) char smem[MB * KP * 2];     // 32 KiB operand stage
  __shared__ __align__(16) float part[2][4][16][36];   // [kh][gate][col][row+pad] 18.4 KiB

  int* flags   = (int*)ws;                                        // [NCH][64][FSTRIDE]
  _Float16* h1 = (_Float16*)(ws + WS_H1_OFF);                     // [R1][B_SZ][KP]
  _Float16* h2 = (_Float16*)(ws + WS_H2_OFF);                     // [R2][B_SZ][KP]

  const int tid  = threadIdx.x;
  const int lane = tid & 63;
  const int wave = tid >> 6;
  const int gp   = wave & 1;           // gate pair: gates {2gp, 2gp+1}
  const int kh   = wave >> 1;          // K-half: [kh*256, kh*256+256)
  const int wg   = blockIdx.x;
  // CO-SCHEDULING DECODE: CU c hosts wg=c (L1) and wg=c+256 (L2) of the SAME
  // chunk — phase-offset layers overlap. All sync stays agent-scope (L3).
  const int mb    = wg & 7;            // chunk 0..7 (spread across XCDs)
  const bool isL2 = (wg >> 8) != 0;    // first 256 WGs = L1, second 256 = L2
  const int nb    = (wg >> 3) & 31;    // hidden block 0..31 (16 units)
  int* flags_c    = flags + mb * 64 * FSTRIDE;
  int* my_flag    = flags + (mb * 64 + (isL2 ? 32 : 0) + nb) * FSTRIDE;

  const int j0   = nb << 4;
  const int col  = lane & 15;
  const int krow = lane >> 4;
  const int jj   = j0 + col;
  const bool jvalid = (jj < F_DIM);

  const float* wA = isL2 ? w_ih2 : w_ih1;
  const float* wB = isL2 ? w_hh2 : w_hh1;
  const float* bi = isL2 ? b_ih2 : b_ih1;
  const float* bh = isL2 ? b_hh2 : b_hh1;

  // B-fragments: 2 gates x K-half per wave, both matrices
  h8 wfA[2][8], wfB[2][8];
  float bias2[2];
  #pragma unroll
  for (int gl = 0; gl < 2; ++gl) {
    const int g    = gp * 2 + gl;
    const int nrow = g * F_DIM + jj;
    #pragma unroll
    for (int ks = 0; ks < 8; ++ks) {
      h8 a, b;
      #pragma unroll
      for (int e = 0; e < 8; ++e) {
        int k = ((kh * 8 + ks) << 5) + (krow << 3) + e;
        bool ok = jvalid && (k < F_DIM);
        a[e] = (_Float16)(ok ? wA[nrow * F_DIM + k] : 0.0f);
        b[e] = (_Float16)(ok ? wB[nrow * F_DIM + k] : 0.0f);
      }
      wfA[gl][ks] = a; wfB[gl][ks] = b;
    }
    bias2[gl] = (kh == 0 && jvalid) ? (bi[nrow] + bh[nrow]) : 0.0f;
  }

  // cell-update mapping: thread owns (row = tid>>3, cols j0 + (tid&7)*2 .. +1)
  const int urow = tid >> 3;           // 0..31
  const int q    = tid & 7;
  float wl2[2];
  #pragma unroll
  for (int cc = 0; cc < 2; ++cc) {
    int j = j0 + (q << 1) + cc;
    wl2[cc] = (isL2 && j < F_DIM) ? w_lin[j] : 0.0f;
  }

  float cst[2] = {0.f, 0.f};
  f4 acc[2][2];

  if (!isL2) {
    // ================= Layer-1 pipeline =================
    u32x4 hstg[8];
    if (x16) stage_x16(smem, x16 + ((size_t)0 * B_SZ + mb * MB) * KP, tid);
    else     stage_x  (smem, x + (size_t)mb * MB * F_DIM, tid);
    __syncthreads();

    for (int t = 0; t < T_ST; ++t) {
      #pragma unroll
      for (int gl = 0; gl < 2; ++gl)
        #pragma unroll
        for (int mt = 0; mt < 2; ++mt)
          acc[gl][mt] = (f4){bias2[gl], bias2[gl], bias2[gl], bias2[gl]};

      if (t > 0) {
        // chain: poll -> issue h1(t-1) -> gemm1 (hides h latency) -> LDS -> gemm2
        poll_sync(flags_c, t, t - 7, tid);
        issue_h8(hstg, h1 + ((size_t)((t - 1) % R1) * B_SZ + mb * MB) * KP, tid);
        gemm_tile2(acc, smem, wfA, col, krow, kh);   // x(t) path
        __syncthreads();             // gemm1 smem readers done
        wait_vm0();
        write_h8(smem, hstg, tid);
        __syncthreads();
        gemm_tile2(acc, smem, wfB, col, krow, kh);   // h path
      } else {
        gemm_tile2(acc, smem, wfA, col, krow, kh);
      }

      // publish partials
      #pragma unroll
      for (int gl = 0; gl < 2; ++gl)
        #pragma unroll
        for (int mt = 0; mt < 2; ++mt)
          *(f4*)&part[kh][gp * 2 + gl][col][mt * 16 + (krow << 2)] = acc[gl][mt];
      __syncthreads();

      // cell update + h1 store
      float hv[2];
      #pragma unroll
      for (int cc = 0; cc < 2; ++cc) {
        int lc = (q << 1) + cc;
        float gi = part[0][0][lc][urow] + part[1][0][lc][urow];
        float gf = part[0][1][lc][urow] + part[1][1][lc][urow];
        float gg = part[0][2][lc][urow] + part[1][2][lc][urow];
        float go = part[0][3][lc][urow] + part[1][3][lc][urow];
        float cn = sigm(gf) * cst[cc] + sigm(gi) * tanh_f(gg);
        cst[cc] = cn;
        hv[cc] = sigm(go) * tanh_f(cn);
      }
      unsigned int hb;
      {
        unsigned int s0 = __builtin_bit_cast(unsigned short, (_Float16)hv[0]);
        unsigned int s1 = __builtin_bit_cast(unsigned short, (_Float16)hv[1]);
        hb = s0 | (s1 << 16);
      }
      int bg = mb * MB + urow;
      {
        char* dst = (char*)(h1 + (size_t)(t % R1) * B_SZ * KP +
                            (size_t)bg * KP + j0 + (q << 1));
        asm volatile("global_store_dword %0, %1, off sc0 sc1"
                     :: "v"(dst), "v"(hb) : "memory");
      }
      asm volatile("s_waitcnt vmcnt(0)" ::: "memory");
      __syncthreads();
      if (tid == 0)
        __hip_atomic_store(my_flag, t + 1,
                           __ATOMIC_RELAXED, __HIP_MEMORY_SCOPE_AGENT);

      // tail (off-chain): stage x(t+1)
      if (t + 1 < T_ST) {
        if (x16) stage_x16(smem, x16 + ((size_t)(t + 1) * B_SZ + mb * MB) * KP, tid);
        else     stage_x  (smem, x + ((size_t)(t + 1) * B_SZ + mb * MB) * F_DIM, tid);
        // next-iteration poll_sync barrier orders these writes vs gemm1 reads
      }
    }
  } else {
    // ================= Layer-2 pipeline =================
    u32x4 hstg[8], hstg2[8];
    for (int t = 0; t < T_ST; ++t) {
      #pragma unroll
      for (int gl = 0; gl < 2; ++gl)
        #pragma unroll
        for (int mt = 0; mt < 2; ++mt)
          acc[gl][mt] = (f4){bias2[gl], bias2[gl], bias2[gl], bias2[gl]};

      // need: L1 done step t (flag>=t+1); L2 peers done step t-1 (flag>=t)
      poll_sync(flags_c, t + 1, t, tid);
      // issue BOTH tiles back-to-back; single drain (one exposed RT total)
      if (t > 0) issue_h8(hstg2, h2 + ((size_t)((t - 1) % R2) * B_SZ + mb * MB) * KP, tid);
      issue_h8(hstg, h1 + ((size_t)(t % R1) * B_SZ + mb * MB) * KP, tid);
      wait_vm0();
      if (t > 0) {
        write_h8(smem, hstg2, tid);  // prev-iter readers joined at poll barrier
        __syncthreads();
        gemm_tile2(acc, smem, wfB, col, krow, kh);   // h2 path first
        __syncthreads();             // gemm readers done before restage
      }
      write_h8(smem, hstg, tid);
      __syncthreads();
      gemm_tile2(acc, smem, wfA, col, krow, kh);     // h1 path

      // publish partials
      #pragma unroll
      for (int gl = 0; gl < 2; ++gl)
        #pragma unroll
        for (int mt = 0; mt < 2; ++mt)
          *(f4*)&part[kh][gp * 2 + gl][col][mt * 16 + (krow << 2)] = acc[gl][mt];
      __syncthreads();

      // cell update + h2 store
      float hv[2];
      #pragma unroll
      for (int cc = 0; cc < 2; ++cc) {
        int lc = (q << 1) + cc;
        float gi = part[0][0][lc][urow] + part[1][0][lc][urow];
        float gf = part[0][1][lc][urow] + part[1][1][lc][urow];
        float gg = part[0][2][lc][urow] + part[1][2][lc][urow];
        float go = part[0][3][lc][urow] + part[1][3][lc][urow];
        float cn = sigm(gf) * cst[cc] + sigm(gi) * tanh_f(gg);
        cst[cc] = cn;
        hv[cc] = sigm(go) * tanh_f(cn);
      }
      unsigned int hb;
      {
        unsigned int s0 = __builtin_bit_cast(unsigned short, (_Float16)hv[0]);
        unsigned int s1 = __builtin_bit_cast(unsigned short, (_Float16)hv[1]);
        hb = s0 | (s1 << 16);
      }
      int bg = mb * MB + urow;
      {
        char* dst = (char*)(h2 + (size_t)(t % R2) * B_SZ * KP +
                            (size_t)bg * KP + j0 + (q << 1));
        asm volatile("global_store_dword %0, %1, off sc0 sc1"
                     :: "v"(dst), "v"(hb) : "memory");
      }
      asm volatile("s_waitcnt vmcnt(0)" ::: "memory");
      __syncthreads();
      if (tid == 0)
        __hip_atomic_store(my_flag, t + 1,
                           __ATOMIC_RELAXED, __HIP_MEMORY_SCOPE_AGENT);

      // contended output atomics AFTER the flag -> off the critical path
      float py = hv[0] * wl2[0] + hv[1] * wl2[1];
      py += __shfl_xor(py, 1);
      py += __shfl_xor(py, 2);
      py += __shfl_xor(py, 4);
      if (q == 0) atomicAdd(out + (size_t)bg * T_ST + t, py);
    }
  }
}

extern "C" void kernel_launch(void* const* d_in, const int* in_sizes, int n_in,
                              void* d_out, int out_size, void* d_ws, size_t ws_size,
                              hipStream_t stream) {
  (void)in_sizes; (void)n_in; (void)out_size;
  const float* x     = (const float*)d_in[0];
  const float* w_ih1 = (const float*)d_in[1];
  const float* w_hh1 = (const float*)d_in[2];
  const float* b_ih1 = (const float*)d_in[3];
  const float* b_hh1 = (const float*)d_in[4];
  const float* w_ih2 = (const float*)d_in[5];
  const float* w_hh2 = (const float*)d_in[6];
  const float* b_ih2 = (const float*)d_in[7];
  const float* b_hh2 = (const float*)d_in[8];
  const float* w_lin = (const float*)d_in[9];
  const float* b_lin = (const float*)d_in[10];
  float* out = (float*)d_out;
  char* ws   = (char*)d_ws;

  const bool have_x16 = ws_size >= WS_X16_OFF + X16_BYTES;
  _Float16* x16 = have_x16 ? (_Float16*)(ws + WS_X16_OFF) : nullptr;

  hipLaunchKernelGGL(init_kernel, dim3((B_SZ * T_ST + 255) / 256), dim3(256), 0, stream,
                     out, b_lin, (int*)ws);
  if (have_x16) {
    const int total_thr = T_ST * B_SZ * 64;   // 8 elems per thread
    hipLaunchKernelGGL(cvt_x_kernel, dim3(total_thr / 256), dim3(256), 0, stream,
                       x, x16);
  }
  hipLaunchKernelGGL(lstm_kernel, dim3(NWG), dim3(256), 0, stream,
                     x, x16, w_ih1, w_hh1, b_ih1, b_hh1,
                     w_ih2, w_hh2, b_ih2, b_hh2,
                     w_lin, out, ws);
}

// Round 21
// 2400.081 us; speedup vs baseline: 2.3136x; 1.3858x over previous
//
#include <hip/hip_runtime.h>
#include <hip/hip_fp16.h>

#define F_DIM 510
#define KP    512      // padded K
#define B_SZ  256
#define T_ST  512
#define MB    32       // batch rows per chunk (8 chunks)
#define NCH   8
#define NWG   512      // 2 WGs per CU
#define R1    8        // h1 ring depth
#define R2    4        // h2 ring depth
#define FSTRIDE 32     // ints per flag slot (128B; de-hotspot slices)

#define WS_FLAGS_BYTES ((size_t)NCH * 64 * FSTRIDE * 4)   // 64 KiB
#define WS_H1_OFF  WS_FLAGS_BYTES
#define WS_H2_OFF  (WS_H1_OFF + (size_t)R1 * B_SZ * KP * 2)
#define WS_X16_OFF (WS_H2_OFF + (size_t)R2 * B_SZ * KP * 2)
#define X16_BYTES  ((size_t)T_ST * B_SZ * KP * 2)

typedef _Float16 h8 __attribute__((ext_vector_type(8)));
typedef float    f4 __attribute__((ext_vector_type(4)));
typedef unsigned int u32x4 __attribute__((ext_vector_type(4)));
typedef unsigned long long u64;

__device__ __forceinline__ float sigm(float v)   { return 1.0f / (1.0f + __expf(-v)); }
__device__ __forceinline__ float tanh_f(float v) { return 1.0f - 2.0f / (__expf(2.0f * v) + 1.0f); }

__global__ void init_kernel(float* __restrict__ out, const float* __restrict__ b_lin,
                            int* __restrict__ flags) {
  int i = blockIdx.x * blockDim.x + threadIdx.x;
  if (i < NCH * 64 * FSTRIDE) flags[i] = 0;
  if (i < B_SZ * T_ST) out[i] = b_lin[0];
}

// pre-pass: x fp32 [T*B][F_DIM] -> fp16 [T*B][KP] (zero-padded)
__global__ void cvt_x_kernel(const float* __restrict__ x, _Float16* __restrict__ x16) {
  size_t i = (size_t)blockIdx.x * blockDim.x + threadIdx.x;   // 0 .. T*B*64-1
  int g = (int)(i & 63);
  size_t s = i >> 6;
  int k0 = g << 3;
  const float* src = x + s * F_DIM + k0;
  h8 v;
  if (k0 + 8 <= F_DIM) {
    #pragma unroll
    for (int e = 0; e < 4; ++e) {
      float2 p = *(const float2*)(src + 2 * e);
      v[2 * e]     = (_Float16)p.x;
      v[2 * e + 1] = (_Float16)p.y;
    }
  } else {
    #pragma unroll
    for (int e = 0; e < 8; ++e) v[e] = (_Float16)((k0 + e < F_DIM) ? src[e] : 0.0f);
  }
  *(h8*)(x16 + s * KP + k0) = v;
}

// stage fp32 x [MB][F_DIM] -> LDS fp16 [MB][KP], XOR-swizzled (fallback path)
__device__ __forceinline__ void stage_x(char* st, const float* __restrict__ src, int tid) {
  #pragma unroll
  for (int i = 0; i < 8; ++i) {
    int c  = tid + (i << 8);
    int m  = c >> 6;
    int kb = (c & 63) << 3;
    h8 v;
    const float* s = src + m * F_DIM + kb;
    if (kb + 8 <= F_DIM) {
      #pragma unroll
      for (int e = 0; e < 4; ++e) {
        float2 p = *(const float2*)(s + 2 * e);
        v[2 * e]     = (_Float16)p.x;
        v[2 * e + 1] = (_Float16)p.y;
      }
    } else {
      #pragma unroll
      for (int e = 0; e < 8; ++e) v[e] = (_Float16)((kb + e < F_DIM) ? s[e] : 0.0f);
    }
    int byte = ((m * KP + kb) << 1) ^ ((m & 7) << 4);
    *(h8*)(st + byte) = v;
  }
}

// stage fp16 x16 [MB][KP] -> LDS, XOR-swizzled (plain cached loads; split issue/use)
__device__ __forceinline__ void stage_x16(char* st, const _Float16* __restrict__ src, int tid) {
  u32x4 v[8];
  const u32x4* s = (const u32x4*)src;
  #pragma unroll
  for (int i = 0; i < 8; ++i) v[i] = s[tid + (i << 8)];
  #pragma unroll
  for (int i = 0; i < 8; ++i) {
    int c  = tid + (i << 8);
    int m  = c >> 6;
    int kc = c & 63;
    int byte = (m * 1024 + (kc << 4)) ^ ((m & 7) << 4);
    *(u32x4*)(st + byte) = v[i];
  }
}

// issue 8 PIPELINED coherent 16B loads (32 KiB tile / 256 threads)
__device__ __forceinline__ void issue_h8(u32x4* v, const _Float16* __restrict__ src, int tid) {
  const u32x4* s = (const u32x4*)src;
  #pragma unroll
  for (int i = 0; i < 8; ++i)
    asm volatile("global_load_dwordx4 %0, %1, off sc0 sc1"
                 : "=&v"(v[i]) : "v"(s + tid + (i << 8)));
}

// single full drain + scheduling fence (rule #18)
__device__ __forceinline__ void wait_vm0() {
  asm volatile("s_waitcnt vmcnt(0)" ::: "memory");
  __builtin_amdgcn_sched_barrier(0);
}

// write registers -> LDS fp16 [MB][KP], XOR-swizzled (16B units)
__device__ __forceinline__ void write_h8(char* st, const u32x4* v, int tid) {
  #pragma unroll
  for (int i = 0; i < 8; ++i) {
    int c  = tid + (i << 8);
    int m  = c >> 6;
    int kc = c & 63;
    int byte = (m * 1024 + (kc << 4)) ^ ((m & 7) << 4);
    *(u32x4*)(st + byte) = v[i];
  }
}

// K-split gemm: wave covers K-slice [kh*256, kh*256+256) for its 2 gates; M=32.
__device__ __forceinline__ void gemm_tile2(f4 (*acc)[2], const char* sm,
                                           const h8 wf[2][8], int col, int krow, int kh) {
  #pragma unroll
  for (int ks = 0; ks < 8; ++ks) {
    #pragma unroll
    for (int mt = 0; mt < 2; ++mt) {
      int lin = mt * 16384 + col * 1024 + (kh * 8 + ks) * 64 + krow * 16;
      h8 af = *(const h8*)(sm + (lin ^ ((col & 7) << 4)));
      acc[0][mt] = __builtin_amdgcn_mfma_f32_16x16x32_f16(af, wf[0][ks], acc[0][mt], 0, 0, 0);
      acc[1][mt] = __builtin_amdgcn_mfma_f32_16x16x32_f16(af, wf[1][ks], acc[1][mt], 0, 0, 0);
    }
  }
}

// wave-0-only poll over spread flag slots, per-lane exit, sleep between probes;
// barrier releases the other waves. (agent-scope: L3 coherence point — REQUIRED)
__device__ __forceinline__ void poll_sync(const int* fl, int thr_lo, int thr_hi, int tid) {
  if (tid < 64) {
    const int thr = (tid < 32) ? thr_lo : thr_hi;
    const int* p = fl + tid * FSTRIDE;
    while (__hip_atomic_load(p, __ATOMIC_RELAXED, __HIP_MEMORY_SCOPE_AGENT) < thr)
      __builtin_amdgcn_s_sleep(2);
  }
  __syncthreads();
}

__launch_bounds__(256, 2)
__global__ void lstm_kernel(
    const float* __restrict__ x, const _Float16* __restrict__ x16,
    const float* __restrict__ w_ih1, const float* __restrict__ w_hh1,
    const float* __restrict__ b_ih1, const float* __restrict__ b_hh1,
    const float* __restrict__ w_ih2, const float* __restrict__ w_hh2,
    const float* __restrict__ b_ih2, const float* __restrict__ b_hh2,
    const float* __restrict__ w_lin,
    float* __restrict__ out, char* __restrict__ ws)
{
  __shared__ __align__(16) char smem[MB * KP * 2];     // 32 KiB operand stage
  __shared__ __align__(16) float part[2][4][16][36];   // [kh][gate][col][row+pad] 18.4 KiB

  int* flags   = (int*)ws;                                        // [NCH][64][FSTRIDE]
  _Float16* h1 = (_Float16*)(ws + WS_H1_OFF);                     // [R1][B_SZ][KP]
  _Float16* h2 = (_Float16*)(ws + WS_H2_OFF);                     // [R2][B_SZ][KP]

  const int tid  = threadIdx.x;
  const int lane = tid & 63;
  const int wave = tid >> 6;
  const int gp   = wave & 1;           // gate pair: gates {2gp, 2gp+1}
  const int kh   = wave >> 1;          // K-half: [kh*256, kh*256+256)
  const int wg   = blockIdx.x;
  // CO-SCHEDULING DECODE: CU c hosts wg=c (L1) and wg=c+256 (L2) of the SAME
  // chunk — phase-offset layers overlap. All sync stays agent-scope (L3).
  const int mb    = wg & 7;            // chunk 0..7 (spread across XCDs)
  const bool isL2 = (wg >> 8) != 0;    // first 256 WGs = L1, second 256 = L2
  const int nb    = (wg >> 3) & 31;    // hidden block 0..31 (16 units)
  int* flags_c    = flags + mb * 64 * FSTRIDE;
  int* my_flag    = flags + (mb * 64 + (isL2 ? 32 : 0) + nb) * FSTRIDE;

  const int j0   = nb << 4;
  const int col  = lane & 15;
  const int krow = lane >> 4;
  const int jj   = j0 + col;
  const bool jvalid = (jj < F_DIM);

  const float* wA = isL2 ? w_ih2 : w_ih1;
  const float* wB = isL2 ? w_hh2 : w_hh1;
  const float* bi = isL2 ? b_ih2 : b_ih1;
  const float* bh = isL2 ? b_hh2 : b_hh1;

  // B-fragments: 2 gates x K-half per wave, both matrices
  h8 wfA[2][8], wfB[2][8];
  float bias2[2];
  #pragma unroll
  for (int gl = 0; gl < 2; ++gl) {
    const int g    = gp * 2 + gl;
    const int nrow = g * F_DIM + jj;
    #pragma unroll
    for (int ks = 0; ks < 8; ++ks) {
      h8 a, b;
      #pragma unroll
      for (int e = 0; e < 8; ++e) {
        int k = ((kh * 8 + ks) << 5) + (krow << 3) + e;
        bool ok = jvalid && (k < F_DIM);
        a[e] = (_Float16)(ok ? wA[nrow * F_DIM + k] : 0.0f);
        b[e] = (_Float16)(ok ? wB[nrow * F_DIM + k] : 0.0f);
      }
      wfA[gl][ks] = a; wfB[gl][ks] = b;
    }
    bias2[gl] = (kh == 0 && jvalid) ? (bi[nrow] + bh[nrow]) : 0.0f;
  }

  // cell-update mapping: thread owns (row = tid>>3, cols j0 + (tid&7)*2 .. +1)
  const int urow = tid >> 3;           // 0..31
  const int q    = tid & 7;
  float wl2[2];
  #pragma unroll
  for (int cc = 0; cc < 2; ++cc) {
    int j = j0 + (q << 1) + cc;
    wl2[cc] = (isL2 && j < F_DIM) ? w_lin[j] : 0.0f;
  }

  float cst[2] = {0.f, 0.f};
  u32x4 hstg[8];
  f4 acc[2][2];

  if (!isL2) {
    // ================= Layer-1 pipeline =================
    if (x16) stage_x16(smem, x16 + ((size_t)0 * B_SZ + mb * MB) * KP, tid);
    else     stage_x  (smem, x + (size_t)mb * MB * F_DIM, tid);
    __syncthreads();

    for (int t = 0; t < T_ST; ++t) {
      #pragma unroll
      for (int gl = 0; gl < 2; ++gl)
        #pragma unroll
        for (int mt = 0; mt < 2; ++mt)
          acc[gl][mt] = (f4){bias2[gl], bias2[gl], bias2[gl], bias2[gl]};

      if (t > 0) {
        // chain: poll -> issue h1(t-1) -> gemm1 (hides h latency) -> LDS -> gemm2
        poll_sync(flags_c, t, t - 7, tid);
        issue_h8(hstg, h1 + ((size_t)((t - 1) % R1) * B_SZ + mb * MB) * KP, tid);
        gemm_tile2(acc, smem, wfA, col, krow, kh);   // x(t) path
        __syncthreads();             // gemm1 smem readers done
        wait_vm0();
        write_h8(smem, hstg, tid);
        __syncthreads();
        gemm_tile2(acc, smem, wfB, col, krow, kh);   // h path
      } else {
        gemm_tile2(acc, smem, wfA, col, krow, kh);
      }

      // publish partials
      #pragma unroll
      for (int gl = 0; gl < 2; ++gl)
        #pragma unroll
        for (int mt = 0; mt < 2; ++mt)
          *(f4*)&part[kh][gp * 2 + gl][col][mt * 16 + (krow << 2)] = acc[gl][mt];
      __syncthreads();

      // cell update + h1 store
      float hv[2];
      #pragma unroll
      for (int cc = 0; cc < 2; ++cc) {
        int lc = (q << 1) + cc;
        float gi = part[0][0][lc][urow] + part[1][0][lc][urow];
        float gf = part[0][1][lc][urow] + part[1][1][lc][urow];
        float gg = part[0][2][lc][urow] + part[1][2][lc][urow];
        float go = part[0][3][lc][urow] + part[1][3][lc][urow];
        float cn = sigm(gf) * cst[cc] + sigm(gi) * tanh_f(gg);
        cst[cc] = cn;
        hv[cc] = sigm(go) * tanh_f(cn);
      }
      unsigned int hb;
      {
        unsigned int s0 = __builtin_bit_cast(unsigned short, (_Float16)hv[0]);
        unsigned int s1 = __builtin_bit_cast(unsigned short, (_Float16)hv[1]);
        hb = s0 | (s1 << 16);
      }
      int bg = mb * MB + urow;
      {
        char* dst = (char*)(h1 + (size_t)(t % R1) * B_SZ * KP +
                            (size_t)bg * KP + j0 + (q << 1));
        asm volatile("global_store_dword %0, %1, off sc0 sc1"
                     :: "v"(dst), "v"(hb) : "memory");
      }
      asm volatile("s_waitcnt vmcnt(0)" ::: "memory");
      __syncthreads();
      if (tid == 0)
        __hip_atomic_store(my_flag, t + 1,
                           __ATOMIC_RELAXED, __HIP_MEMORY_SCOPE_AGENT);

      // tail (off-chain): stage x(t+1)
      if (t + 1 < T_ST) {
        if (x16) stage_x16(smem, x16 + ((size_t)(t + 1) * B_SZ + mb * MB) * KP, tid);
        else     stage_x  (smem, x + ((size_t)(t + 1) * B_SZ + mb * MB) * F_DIM, tid);
        // next-iteration poll_sync barrier orders these writes vs gemm1 reads
      }
    }
  } else {
    // ================= Layer-2 pipeline =================
    for (int t = 0; t < T_ST; ++t) {
      #pragma unroll
      for (int gl = 0; gl < 2; ++gl)
        #pragma unroll
        for (int mt = 0; mt < 2; ++mt)
          acc[gl][mt] = (f4){bias2[gl], bias2[gl], bias2[gl], bias2[gl]};

      // need: L1 done step t (flag>=t+1); L2 peers done step t-1 (flag>=t)
      poll_sync(flags_c, t + 1, t, tid);
      issue_h8(hstg, h1 + ((size_t)(t % R1) * B_SZ + mb * MB) * KP, tid);
      wait_vm0();
      write_h8(smem, hstg, tid);     // prev-iter readers joined at poll barrier
      __syncthreads();
      if (t > 0)                     // h2(t-1) loads; latency hides under GEMM1
        issue_h8(hstg, h2 + ((size_t)((t - 1) % R2) * B_SZ + mb * MB) * KP, tid);
      gemm_tile2(acc, smem, wfA, col, krow, kh);
      if (t > 0) {
        __syncthreads();             // gemm1 readers done
        wait_vm0();
        write_h8(smem, hstg, tid);
        __syncthreads();
        gemm_tile2(acc, smem, wfB, col, krow, kh);
      }

      // publish partials
      #pragma unroll
      for (int gl = 0; gl < 2; ++gl)
        #pragma unroll
        for (int mt = 0; mt < 2; ++mt)
          *(f4*)&part[kh][gp * 2 + gl][col][mt * 16 + (krow << 2)] = acc[gl][mt];
      __syncthreads();

      // cell update + h2 store
      float hv[2];
      #pragma unroll
      for (int cc = 0; cc < 2; ++cc) {
        int lc = (q << 1) + cc;
        float gi = part[0][0][lc][urow] + part[1][0][lc][urow];
        float gf = part[0][1][lc][urow] + part[1][1][lc][urow];
        float gg = part[0][2][lc][urow] + part[1][2][lc][urow];
        float go = part[0][3][lc][urow] + part[1][3][lc][urow];
        float cn = sigm(gf) * cst[cc] + sigm(gi) * tanh_f(gg);
        cst[cc] = cn;
        hv[cc] = sigm(go) * tanh_f(cn);
      }
      unsigned int hb;
      {
        unsigned int s0 = __builtin_bit_cast(unsigned short, (_Float16)hv[0]);
        unsigned int s1 = __builtin_bit_cast(unsigned short, (_Float16)hv[1]);
        hb = s0 | (s1 << 16);
      }
      int bg = mb * MB + urow;
      {
        char* dst = (char*)(h2 + (size_t)(t % R2) * B_SZ * KP +
                            (size_t)bg * KP + j0 + (q << 1));
        asm volatile("global_store_dword %0, %1, off sc0 sc1"
                     :: "v"(dst), "v"(hb) : "memory");
      }
      asm volatile("s_waitcnt vmcnt(0)" ::: "memory");
      __syncthreads();
      if (tid == 0)
        __hip_atomic_store(my_flag, t + 1,
                           __ATOMIC_RELAXED, __HIP_MEMORY_SCOPE_AGENT);

      // contended output atomics AFTER the flag -> off the critical path
      float py = hv[0] * wl2[0] + hv[1] * wl2[1];
      py += __shfl_xor(py, 1);
      py += __shfl_xor(py, 2);
      py += __shfl_xor(py, 4);
      if (q == 0) atomicAdd(out + (size_t)bg * T_ST + t, py);
    }
  }
}

extern "C" void kernel_launch(void* const* d_in, const int* in_sizes, int n_in,
                              void* d_out, int out_size, void* d_ws, size_t ws_size,
                              hipStream_t stream) {
  (void)in_sizes; (void)n_in; (void)out_size;
  const float* x     = (const float*)d_in[0];
  const float* w_ih1 = (const float*)d_in[1];
  const float* w_hh1 = (const float*)d_in[2];
  const float* b_ih1 = (const float*)d_in[3];
  const float* b_hh1 = (const float*)d_in[4];
  const float* w_ih2 = (const float*)d_in[5];
  const float* w_hh2 = (const float*)d_in[6];
  const float* b_ih2 = (const float*)d_in[7];
  const float* b_hh2 = (const float*)d_in[8];
  const float* w_lin = (const float*)d_in[9];
  const float* b_lin = (const float*)d_in[10];
  float* out = (float*)d_out;
  char* ws   = (char*)d_ws;

  const bool have_x16 = ws_size >= WS_X16_OFF + X16_BYTES;
  _Float16* x16 = have_x16 ? (_Float16*)(ws + WS_X16_OFF) : nullptr;

  hipLaunchKernelGGL(init_kernel, dim3((B_SZ * T_ST + 255) / 256), dim3(256), 0, stream,
                     out, b_lin, (int*)ws);
  if (have_x16) {
    const int total_thr = T_ST * B_SZ * 64;   // 8 elems per thread
    hipLaunchKernelGGL(cvt_x_kernel, dim3(total_thr / 256), dim3(256), 0, stream,
                       x, x16);
  }
  hipLaunchKernelGGL(lstm_kernel, dim3(NWG), dim3(256), 0, stream,
                     x, x16, w_ih1, w_hh1, b_ih1, b_hh1,
                     w_ih2, w_hh2, b_ih2, b_hh2,
                     w_lin, out, ws);
}